// Round 15
// baseline (469.392 us; speedup 1.0000x reference)
//
#include <hip/hip_runtime.h>
#include <hip/hip_bf16.h>

#define BATCH 4
#define CIN 64
#define HH 352
#define WW 1216
#define OCH 8
#define OHH 354
#define OWW 1218
#define HW (HH * WW)

#define BH 16       // output rows per block
#define BW 32       // output cols per block
#define FR 18       // staged rows (halo)
#define FC 34       // staged cols (halo)
#define NPOS (FR * FC)   // 612
#define NTHR 256
#define NIT 10
#define GX 38            // WW/BW
#define GY 22            // HH/BH
#define NWG (GX * GY * BATCH)   // 3344 = 8 * 418
#define CPX (NWG / 8)           // 418 blocks per XCD

typedef short bf16x8 __attribute__((ext_vector_type(8)));
typedef float f32x4  __attribute__((ext_vector_type(4)));

// fp32 -> bf16 round-to-nearest-even (branchless, finite inputs)
static __device__ __forceinline__ unsigned f2bf(float x) {
    unsigned u = __float_as_uint(x);
    return (u + 0x7FFFu + ((u >> 16) & 1u)) >> 16;
}

// Bake weights into exact MFMA B-fragment layout (bf16, BN-folded, oc>=8 zero):
// wB[(tap*2+cc)*64 + lane] = 8 bf16: B[k = hi*8+j][col = oc], k-channel = cc*32+hi*8+j
__global__ void repack_kernel(const float* __restrict__ conv_w,
                              const float* __restrict__ gamma,
                              const float* __restrict__ beta,
                              const float* __restrict__ mean,
                              const float* __restrict__ var,
                              unsigned short* __restrict__ wB,
                              float* __restrict__ bias)
{
    int tid = blockIdx.x * 256 + threadIdx.x;
    if (tid < 18 * 64) {
        int tc = tid >> 6;          // tap*2 + cc
        int lane = tid & 63;
        int tap = tc >> 1, cc = tc & 1;
        int oc = lane & 15, hi = lane >> 4;
        unsigned v[8];
#pragma unroll
        for (int j = 0; j < 8; ++j) {
            float w = 0.f;
            if (oc < 8) {
                int c = cc * 32 + hi * 8 + j;
                float scl = gamma[oc] * rsqrtf(var[oc] + 1e-5f);
                w = conv_w[((size_t)oc * CIN + c) * 9 + tap] * scl;
            }
            v[j] = f2bf(w);
        }
        uint4 pk;
        pk.x = v[0] | (v[1] << 16);
        pk.y = v[2] | (v[3] << 16);
        pk.z = v[4] | (v[5] << 16);
        pk.w = v[6] | (v[7] << 16);
        ((uint4*)wB)[tid] = pk;
    }
    if (tid < OCH) {
        float scl = gamma[tid] * rsqrtf(var[tid] + 1e-5f);
        bias[tid] = beta[tid] - mean[tid] * scl;
    }
}

// Zero only the uncovered border ring of each (b,t) OUTPUT plane.
__global__ void border_kernel(float* __restrict__ out)
{
    const int bt = blockIdx.x;          // 0..35
    const int t = bt % 9;
    const int i = t / 3, j = t % 3;
    float* pl = out + (size_t)bt * OHH * OWW;
    const int r0 = (i == 0) ? HH : 0;
    const int r1 = (i == 2) ? 1 : (OHH - 1);
    const int c0 = (j == 0) ? WW : 0;
    const int c1 = (j == 2) ? 1 : (OWW - 1);
    const int nrow = 2 * OWW;
    for (int idx = threadIdx.x; idx < 2 * OWW + 2 * OHH; idx += blockDim.x) {
        if (idx < nrow) {
            int r = (idx < OWW) ? r0 : r1;
            int c = (idx < OWW) ? idx : idx - OWW;
            pl[(size_t)r * OWW + c] = 0.f;
        } else {
            int k = idx - nrow;
            int c = (k < OHH) ? c0 : c1;
            int r = (k < OHH) ? k : k - OHH;
            pl[(size_t)r * OWW + c] = 0.f;
        }
    }
}

__global__ __launch_bounds__(NTHR, 4)   // 4 blocks/CU: 4x39.4KB LDS = 158KB, VGPR<=128
void conv_mfma(const float* __restrict__ feature,
               const unsigned short* __restrict__ wB,
               const float* __restrict__ bias,
               float* __restrict__ out)
{
    __shared__ uint4 sF[NPOS * 4];   // 39424 B, single-buffered (r12 structure)

    // Bijective XCD swizzle (nwg = 3344 = 8*418): each XCD gets a contiguous
    // 418-block range -> neighbor tiles share halo lines in its L2.
    const int lin = blockIdx.x;
    const int wg  = (lin & 7) * CPX + (lin >> 3);
    const int bx  = wg % GX;
    const int byz = wg / GX;
    const int by  = byz % GY;
    const int b   = byz / GY;

    const int tid  = threadIdx.x;
    const int wave = tid >> 6;
    const int lane = tid & 63;
    const int oc   = lane & 15;
    const int hi   = lane >> 4;
    const int h0 = by * BH;
    const int w0 = bx * BW;

    const float* fb = feature + (size_t)b * CIN * HW;
    const int soct = tid & 3;
    const int p0   = tid >> 2;

    f32x4 acc[4][2];
#pragma unroll
    for (int rr = 0; rr < 4; ++rr)
#pragma unroll
        for (int cg = 0; cg < 2; ++cg) acc[rr][cg] = (f32x4)0.f;

#pragma unroll 1
    for (int cc = 0; cc < 2; ++cc) {
        if (cc) __syncthreads();
        const float* chbase = fb + (size_t)(cc * 32 + soct * 8) * HW;
        float v[NIT][8];
        float msk[NIT];
        int   cps[NIT];
#pragma unroll
        for (int it = 0; it < NIT; ++it) {
            int pos = p0 + it * 64;
            int cp = (pos < NPOS) ? pos : (NPOS - 1);   // tail: benign duplicate
            int fr = cp / FC;
            int fc = cp - fr * FC;
            int gh = h0 - 1 + fr, gw = w0 - 1 + fc;
            bool ok = ((unsigned)gh < (unsigned)HH) && ((unsigned)gw < (unsigned)WW);
            int sgh = min(max(gh, 0), HH - 1);
            int sgw = min(max(gw, 0), WW - 1);
            const float* sp = chbase + sgh * WW + sgw;
#pragma unroll
            for (int j = 0; j < 8; ++j) v[it][j] = sp[(size_t)j * HW];
            msk[it] = ok ? 1.f : 0.f;
            cps[it] = cp;
        }
        bf16x8 bwl[9];
#pragma unroll
        for (int t = 0; t < 9; ++t)
            bwl[t] = ((const bf16x8*)wB)[(t * 2 + cc) * 64 + lane];
#pragma unroll
        for (int it = 0; it < NIT; ++it) {
            float mk = msk[it];
            uint4 pk;
            pk.x = f2bf(v[it][0] * mk) | (f2bf(v[it][1] * mk) << 16);
            pk.y = f2bf(v[it][2] * mk) | (f2bf(v[it][3] * mk) << 16);
            pk.z = f2bf(v[it][4] * mk) | (f2bf(v[it][5] * mk) << 16);
            pk.w = f2bf(v[it][6] * mk) | (f2bf(v[it][7] * mk) << 16);
            int cp = cps[it];
            sF[cp * 4 + (soct ^ ((cp >> 1) & 3))] = pk;
        }
        __syncthreads();
#pragma unroll
        for (int t = 0; t < 9; ++t) {
            const int dh = t / 3, dw = t % 3;
#pragma unroll
            for (int rr = 0; rr < 4; ++rr) {
                const int fr = wave * 4 + rr + dh;
#pragma unroll
                for (int cg = 0; cg < 2; ++cg) {
                    const int fc = cg * 16 + oc + dw;
                    const int pp = fr * FC + fc;
                    bf16x8 av = *reinterpret_cast<const bf16x8*>(&sF[pp * 4 + (hi ^ ((pp >> 1) & 3))]);
                    acc[rr][cg] = __builtin_amdgcn_mfma_f32_16x16x32_bf16(av, bwl[t], acc[rr][cg], 0, 0, 0);
                }
            }
        }
    }

    // ---- epilogue: bias, L1-normalize across oc (16-lane shfl), mid, scatter ----
    const float myb = (oc < 8) ? bias[oc] : 0.f;
    const int t = (oc < 8) ? ((oc < 4) ? oc : oc + 1) : 4;
    const bool dow = (oc <= 8);
    const int ii = t / 3, jj = t % 3;
    float* pl = out + ((size_t)(b * 9 + t) * OHH + ii) * OWW + jj;

#pragma unroll
    for (int rr = 0; rr < 4; ++rr) {
        const int h = h0 + wave * 4 + rr;
#pragma unroll
        for (int cg = 0; cg < 2; ++cg) {
#pragma unroll
            for (int reg = 0; reg < 4; ++reg) {
                float vv = acc[rr][cg][reg] + myb;   // lanes oc>=8: 0
                float av = fabsf(vv);
                float sv = vv;
                av += __shfl_xor(av, 1);  sv += __shfl_xor(sv, 1);
                av += __shfl_xor(av, 2);  sv += __shfl_xor(sv, 2);
                av += __shfl_xor(av, 4);  sv += __shfl_xor(sv, 4);
                av += __shfl_xor(av, 8);  sv += __shfl_xor(sv, 8);
                float inv = 1.0f / av;
                float val = (oc == 8) ? (1.0f - sv * inv) : (vv * inv);
                if (dow) {
                    int w = w0 + cg * 16 + hi * 4 + reg;
                    pl[(size_t)h * OWW + w] = val;
                }
            }
        }
    }
}

extern "C" void kernel_launch(void* const* d_in, const int* in_sizes, int n_in,
                              void* d_out, int out_size, void* d_ws, size_t ws_size,
                              hipStream_t stream) {
    const float* feature = (const float*)d_in[0];
    const float* conv_w  = (const float*)d_in[1];
    const float* gamma   = (const float*)d_in[2];
    const float* beta    = (const float*)d_in[3];
    const float* mean    = (const float*)d_in[4];
    const float* var     = (const float*)d_in[5];
    float* out = (float*)d_out;

    unsigned short* wB = (unsigned short*)d_ws;    // 18432 B
    float* bias = (float*)((char*)d_ws + 18432);   // 32 B

    border_kernel<<<BATCH * 9, 256, 0, stream>>>(out);
    repack_kernel<<<5, 256, 0, stream>>>(conv_w, gamma, beta, mean, var, wB, bias);
    conv_mfma<<<NWG, NTHR, 0, stream>>>(feature, wB, bias, out);
}

// Round 16
// 219.923 us; speedup vs baseline: 2.1343x; 2.1343x over previous
//
#include <hip/hip_runtime.h>
#include <hip/hip_bf16.h>

#define BATCH 4
#define CIN 64
#define HH 352
#define WW 1216
#define OCH 8
#define OHH 354
#define OWW 1218
#define HW (HH * WW)

#define BH 16       // output rows per block
#define BW 32       // output cols per block
#define FR 18       // staged rows (halo)
#define FC 34       // staged cols (halo)
#define NPOS (FR * FC)   // 612
#define NTHR 256
#define NIT 10
#define GX 38            // WW/BW
#define GY 22            // HH/BH
#define NWG (GX * GY * BATCH)   // 3344 = 8 * 418
#define CPX (NWG / 8)           // 418 blocks per XCD

typedef short bf16x8 __attribute__((ext_vector_type(8)));
typedef float f32x4  __attribute__((ext_vector_type(4)));

// fp32 -> bf16 round-to-nearest-even (branchless, finite inputs)
static __device__ __forceinline__ unsigned f2bf(float x) {
    unsigned u = __float_as_uint(x);
    return (u + 0x7FFFu + ((u >> 16) & 1u)) >> 16;
}

// Bake weights into exact MFMA B-fragment layout (bf16, BN-folded, oc>=8 zero):
// wB[(tap*2+cc)*64 + lane] = 8 bf16: B[k = hi*8+j][col = oc], k-channel = cc*32+hi*8+j
__global__ void repack_kernel(const float* __restrict__ conv_w,
                              const float* __restrict__ gamma,
                              const float* __restrict__ beta,
                              const float* __restrict__ mean,
                              const float* __restrict__ var,
                              unsigned short* __restrict__ wB,
                              float* __restrict__ bias)
{
    int tid = blockIdx.x * 256 + threadIdx.x;
    if (tid < 18 * 64) {
        int tc = tid >> 6;          // tap*2 + cc
        int lane = tid & 63;
        int tap = tc >> 1, cc = tc & 1;
        int oc = lane & 15, hi = lane >> 4;
        unsigned v[8];
#pragma unroll
        for (int j = 0; j < 8; ++j) {
            float w = 0.f;
            if (oc < 8) {
                int c = cc * 32 + hi * 8 + j;
                float scl = gamma[oc] * rsqrtf(var[oc] + 1e-5f);
                w = conv_w[((size_t)oc * CIN + c) * 9 + tap] * scl;
            }
            v[j] = f2bf(w);
        }
        uint4 pk;
        pk.x = v[0] | (v[1] << 16);
        pk.y = v[2] | (v[3] << 16);
        pk.z = v[4] | (v[5] << 16);
        pk.w = v[6] | (v[7] << 16);
        ((uint4*)wB)[tid] = pk;
    }
    if (tid < OCH) {
        float scl = gamma[tid] * rsqrtf(var[tid] + 1e-5f);
        bias[tid] = beta[tid] - mean[tid] * scl;
    }
}

// Zero only the uncovered border ring of each (b,t) OUTPUT plane.
__global__ void border_kernel(float* __restrict__ out)
{
    const int bt = blockIdx.x;          // 0..35
    const int t = bt % 9;
    const int i = t / 3, j = t % 3;
    float* pl = out + (size_t)bt * OHH * OWW;
    const int r0 = (i == 0) ? HH : 0;
    const int r1 = (i == 2) ? 1 : (OHH - 1);
    const int c0 = (j == 0) ? WW : 0;
    const int c1 = (j == 2) ? 1 : (OWW - 1);
    const int nrow = 2 * OWW;
    for (int idx = threadIdx.x; idx < 2 * OWW + 2 * OHH; idx += blockDim.x) {
        if (idx < nrow) {
            int r = (idx < OWW) ? r0 : r1;
            int c = (idx < OWW) ? idx : idx - OWW;
            pl[(size_t)r * OWW + c] = 0.f;
        } else {
            int k = idx - nrow;
            int c = (k < OHH) ? c0 : c1;
            int r = (k < OHH) ? k : k - OHH;
            pl[(size_t)r * OWW + c] = 0.f;
        }
    }
}

__global__ __launch_bounds__(NTHR, 2)   // (256,2): VGPR cap 256 — body needs ~116; lower tiers spill (r3/r14/r15)
void conv_mfma(const float* __restrict__ feature,
               const unsigned short* __restrict__ wB,
               const float* __restrict__ bias,
               float* __restrict__ out)
{
    __shared__ uint4 sF[NPOS * 4];   // 39424 B, single-buffered (r12 structure)

    // Bijective XCD swizzle (nwg = 3344 = 8*418): each XCD gets a contiguous
    // 418-block range -> neighbor tiles share halo lines in its L2.
    // Proven in r14: FETCH 707 -> 320 MB.
    const int lin = blockIdx.x;
    const int wg  = (lin & 7) * CPX + (lin >> 3);
    const int bx  = wg % GX;
    const int byz = wg / GX;
    const int by  = byz % GY;
    const int b   = byz / GY;

    const int tid  = threadIdx.x;
    const int wave = tid >> 6;
    const int lane = tid & 63;
    const int oc   = lane & 15;
    const int hi   = lane >> 4;
    const int h0 = by * BH;
    const int w0 = bx * BW;

    const float* fb = feature + (size_t)b * CIN * HW;
    const int soct = tid & 3;
    const int p0   = tid >> 2;

    f32x4 acc[4][2];
#pragma unroll
    for (int rr = 0; rr < 4; ++rr)
#pragma unroll
        for (int cg = 0; cg < 2; ++cg) acc[rr][cg] = (f32x4)0.f;

#pragma unroll 1
    for (int cc = 0; cc < 2; ++cc) {
        if (cc) __syncthreads();
        const float* chbase = fb + (size_t)(cc * 32 + soct * 8) * HW;
        float v[NIT][8];
        float msk[NIT];
        int   cps[NIT];
#pragma unroll
        for (int it = 0; it < NIT; ++it) {
            int pos = p0 + it * 64;
            int cp = (pos < NPOS) ? pos : (NPOS - 1);   // tail: benign duplicate
            int fr = cp / FC;
            int fc = cp - fr * FC;
            int gh = h0 - 1 + fr, gw = w0 - 1 + fc;
            bool ok = ((unsigned)gh < (unsigned)HH) && ((unsigned)gw < (unsigned)WW);
            int sgh = min(max(gh, 0), HH - 1);
            int sgw = min(max(gw, 0), WW - 1);
            const float* sp = chbase + sgh * WW + sgw;
#pragma unroll
            for (int j = 0; j < 8; ++j) v[it][j] = sp[(size_t)j * HW];
            msk[it] = ok ? 1.f : 0.f;
            cps[it] = cp;
        }
        bf16x8 bwl[9];
#pragma unroll
        for (int t = 0; t < 9; ++t)
            bwl[t] = ((const bf16x8*)wB)[(t * 2 + cc) * 64 + lane];
#pragma unroll
        for (int it = 0; it < NIT; ++it) {
            float mk = msk[it];
            uint4 pk;
            pk.x = f2bf(v[it][0] * mk) | (f2bf(v[it][1] * mk) << 16);
            pk.y = f2bf(v[it][2] * mk) | (f2bf(v[it][3] * mk) << 16);
            pk.z = f2bf(v[it][4] * mk) | (f2bf(v[it][5] * mk) << 16);
            pk.w = f2bf(v[it][6] * mk) | (f2bf(v[it][7] * mk) << 16);
            int cp = cps[it];
            sF[cp * 4 + (soct ^ ((cp >> 1) & 3))] = pk;
        }
        __syncthreads();
#pragma unroll
        for (int t = 0; t < 9; ++t) {
            const int dh = t / 3, dw = t % 3;
#pragma unroll
            for (int rr = 0; rr < 4; ++rr) {
                const int fr = wave * 4 + rr + dh;
#pragma unroll
                for (int cg = 0; cg < 2; ++cg) {
                    const int fc = cg * 16 + oc + dw;
                    const int pp = fr * FC + fc;
                    bf16x8 av = *reinterpret_cast<const bf16x8*>(&sF[pp * 4 + (hi ^ ((pp >> 1) & 3))]);
                    acc[rr][cg] = __builtin_amdgcn_mfma_f32_16x16x32_bf16(av, bwl[t], acc[rr][cg], 0, 0, 0);
                }
            }
        }
    }

    // ---- epilogue: bias, L1-normalize across oc (16-lane shfl), mid, scatter ----
    const float myb = (oc < 8) ? bias[oc] : 0.f;
    const int t = (oc < 8) ? ((oc < 4) ? oc : oc + 1) : 4;
    const bool dow = (oc <= 8);
    const int ii = t / 3, jj = t % 3;
    float* pl = out + ((size_t)(b * 9 + t) * OHH + ii) * OWW + jj;

#pragma unroll
    for (int rr = 0; rr < 4; ++rr) {
        const int h = h0 + wave * 4 + rr;
#pragma unroll
        for (int cg = 0; cg < 2; ++cg) {
#pragma unroll
            for (int reg = 0; reg < 4; ++reg) {
                float vv = acc[rr][cg][reg] + myb;   // lanes oc>=8: 0
                float av = fabsf(vv);
                float sv = vv;
                av += __shfl_xor(av, 1);  sv += __shfl_xor(sv, 1);
                av += __shfl_xor(av, 2);  sv += __shfl_xor(sv, 2);
                av += __shfl_xor(av, 4);  sv += __shfl_xor(sv, 4);
                av += __shfl_xor(av, 8);  sv += __shfl_xor(sv, 8);
                float inv = 1.0f / av;
                float val = (oc == 8) ? (1.0f - sv * inv) : (vv * inv);
                if (dow) {
                    int w = w0 + cg * 16 + hi * 4 + reg;
                    pl[(size_t)h * OWW + w] = val;
                }
            }
        }
    }
}

extern "C" void kernel_launch(void* const* d_in, const int* in_sizes, int n_in,
                              void* d_out, int out_size, void* d_ws, size_t ws_size,
                              hipStream_t stream) {
    const float* feature = (const float*)d_in[0];
    const float* conv_w  = (const float*)d_in[1];
    const float* gamma   = (const float*)d_in[2];
    const float* beta    = (const float*)d_in[3];
    const float* mean    = (const float*)d_in[4];
    const float* var     = (const float*)d_in[5];
    float* out = (float*)d_out;

    unsigned short* wB = (unsigned short*)d_ws;    // 18432 B
    float* bias = (float*)((char*)d_ws + 18432);   // 32 B

    border_kernel<<<BATCH * 9, 256, 0, stream>>>(out);
    repack_kernel<<<5, 256, 0, stream>>>(conv_w, gamma, beta, mean, var, wB, bias);
    conv_mfma<<<NWG, NTHR, 0, stream>>>(feature, wB, bias, out);
}

// Round 17
// 212.779 us; speedup vs baseline: 2.2060x; 1.0336x over previous
//
#include <hip/hip_runtime.h>
#include <hip/hip_bf16.h>

#define BATCH 4
#define CIN 64
#define HH 352
#define WW 1216
#define OCH 8
#define OHH 354
#define OWW 1218
#define HW (HH * WW)

#define BH 16       // output rows per block
#define BW 32       // output cols per block
#define FR 18       // staged rows (halo)
#define FC 34       // staged cols (halo)
#define NPOS (FR * FC)   // 612
#define NTHR 256
#define NHALF 5          // staging tasks per half-pass (2 halves = 10 = ceil(2448/256))
#define GX 38            // WW/BW
#define GY 22            // HH/BH
#define NWG (GX * GY * BATCH)   // 3344 = 8 * 418
#define CPX (NWG / 8)           // 418 blocks per XCD

typedef short bf16x8 __attribute__((ext_vector_type(8)));
typedef float f32x4  __attribute__((ext_vector_type(4)));

// fp32 -> bf16 round-to-nearest-even (branchless, finite inputs)
static __device__ __forceinline__ unsigned f2bf(float x) {
    unsigned u = __float_as_uint(x);
    return (u + 0x7FFFu + ((u >> 16) & 1u)) >> 16;
}

// Bake weights into exact MFMA B-fragment layout (bf16, BN-folded, oc>=8 zero):
// wB[(tap*2+cc)*64 + lane] = 8 bf16: B[k = hi*8+j][col = oc], k-channel = cc*32+hi*8+j
__global__ void repack_kernel(const float* __restrict__ conv_w,
                              const float* __restrict__ gamma,
                              const float* __restrict__ beta,
                              const float* __restrict__ mean,
                              const float* __restrict__ var,
                              unsigned short* __restrict__ wB,
                              float* __restrict__ bias)
{
    int tid = blockIdx.x * 256 + threadIdx.x;
    if (tid < 18 * 64) {
        int tc = tid >> 6;          // tap*2 + cc
        int lane = tid & 63;
        int tap = tc >> 1, cc = tc & 1;
        int oc = lane & 15, hi = lane >> 4;
        unsigned v[8];
#pragma unroll
        for (int j = 0; j < 8; ++j) {
            float w = 0.f;
            if (oc < 8) {
                int c = cc * 32 + hi * 8 + j;
                float scl = gamma[oc] * rsqrtf(var[oc] + 1e-5f);
                w = conv_w[((size_t)oc * CIN + c) * 9 + tap] * scl;
            }
            v[j] = f2bf(w);
        }
        uint4 pk;
        pk.x = v[0] | (v[1] << 16);
        pk.y = v[2] | (v[3] << 16);
        pk.z = v[4] | (v[5] << 16);
        pk.w = v[6] | (v[7] << 16);
        ((uint4*)wB)[tid] = pk;
    }
    if (tid < OCH) {
        float scl = gamma[tid] * rsqrtf(var[tid] + 1e-5f);
        bias[tid] = beta[tid] - mean[tid] * scl;
    }
}

// Zero only the uncovered border ring of each (b,t) OUTPUT plane.
__global__ void border_kernel(float* __restrict__ out)
{
    const int bt = blockIdx.x;          // 0..35
    const int t = bt % 9;
    const int i = t / 3, j = t % 3;
    float* pl = out + (size_t)bt * OHH * OWW;
    const int r0 = (i == 0) ? HH : 0;
    const int r1 = (i == 2) ? 1 : (OHH - 1);
    const int c0 = (j == 0) ? WW : 0;
    const int c1 = (j == 2) ? 1 : (OWW - 1);
    const int nrow = 2 * OWW;
    for (int idx = threadIdx.x; idx < 2 * OWW + 2 * OHH; idx += blockDim.x) {
        if (idx < nrow) {
            int r = (idx < OWW) ? r0 : r1;
            int c = (idx < OWW) ? idx : idx - OWW;
            pl[(size_t)r * OWW + c] = 0.f;
        } else {
            int k = idx - nrow;
            int c = (k < OHH) ? c0 : c1;
            int r = (k < OHH) ? k : k - OHH;
            pl[(size_t)r * OWW + c] = 0.f;
        }
    }
}

__global__ __launch_bounds__(NTHR, 2)   // allocator uncapped (body needs what it needs; caps spill — r3/r14/r15)
void conv_mfma(const float* __restrict__ feature,
               const unsigned short* __restrict__ wB,
               const float* __restrict__ bias,
               float* __restrict__ out)
{
    __shared__ uint4 sF[NPOS * 4];   // 39424 B, single-buffered

    // Bijective XCD swizzle (nwg = 3344 = 8*418): FETCH 707 -> 320 MB (r14/r16).
    const int lin = blockIdx.x;
    const int wg  = (lin & 7) * CPX + (lin >> 3);
    const int bx  = wg % GX;
    const int byz = wg / GX;
    const int by  = byz % GY;
    const int b   = byz / GY;

    const int tid  = threadIdx.x;
    const int wave = tid >> 6;
    const int lane = tid & 63;
    const int oc   = lane & 15;
    const int hi   = lane >> 4;
    const int h0 = by * BH;
    const int w0 = bx * BW;

    const float* fb = feature + (size_t)b * CIN * HW;
    const int soct = tid & 3;
    const int p0   = tid >> 2;

    f32x4 acc[4][2];
#pragma unroll
    for (int rr = 0; rr < 4; ++rr)
#pragma unroll
        for (int cg = 0; cg < 2; ++cg) acc[rr][cg] = (f32x4)0.f;

#pragma unroll 1
    for (int cc = 0; cc < 2; ++cc) {
        if (cc) __syncthreads();
        const float* chbase = fb + (size_t)(cc * 32 + soct * 8) * HW;

        bf16x8 bwl[9];
#pragma unroll
        for (int t = 0; t < 9; ++t)
            bwl[t] = ((const bf16x8*)wB)[(t * 2 + cc) * 64 + lane];

        // Two serialized half-passes of 5 tasks: staging buffer 40 regs not 80.
        // unroll 1 keeps the compiler from re-merging the halves (reg pressure).
#pragma unroll 1
        for (int hf = 0; hf < 2; ++hf) {
            float v[NHALF][8];
            float mk5[NHALF];
            int   sl5[NHALF];
#pragma unroll
            for (int it = 0; it < NHALF; ++it) {
                int pos = p0 + (hf * NHALF + it) * 64;
                int cp = (pos < NPOS) ? pos : (NPOS - 1);   // tail: benign duplicate
                int fr = cp / FC;
                int fc = cp - fr * FC;
                int gh = h0 - 1 + fr, gw = w0 - 1 + fc;
                bool ok = ((unsigned)gh < (unsigned)HH) && ((unsigned)gw < (unsigned)WW);
                int sgh = min(max(gh, 0), HH - 1);
                int sgw = min(max(gw, 0), WW - 1);
                const float* sp = chbase + sgh * WW + sgw;
#pragma unroll
                for (int j = 0; j < 8; ++j) v[it][j] = sp[(size_t)j * HW];
                mk5[it] = ok ? 1.f : 0.f;
                sl5[it] = cp * 4 + (soct ^ ((cp >> 1) & 3));
            }
#pragma unroll
            for (int it = 0; it < NHALF; ++it) {
                float mk = mk5[it];
                uint4 pk;
                pk.x = f2bf(v[it][0] * mk) | (f2bf(v[it][1] * mk) << 16);
                pk.y = f2bf(v[it][2] * mk) | (f2bf(v[it][3] * mk) << 16);
                pk.z = f2bf(v[it][4] * mk) | (f2bf(v[it][5] * mk) << 16);
                pk.w = f2bf(v[it][6] * mk) | (f2bf(v[it][7] * mk) << 16);
                sF[sl5[it]] = pk;
            }
        }
        __syncthreads();

#pragma unroll
        for (int t = 0; t < 9; ++t) {
            const int dh = t / 3, dw = t % 3;
#pragma unroll
            for (int rr = 0; rr < 4; ++rr) {
                const int fr = wave * 4 + rr + dh;
#pragma unroll
                for (int cg = 0; cg < 2; ++cg) {
                    const int fc = cg * 16 + oc + dw;
                    const int pp = fr * FC + fc;
                    bf16x8 av = *reinterpret_cast<const bf16x8*>(&sF[pp * 4 + (hi ^ ((pp >> 1) & 3))]);
                    acc[rr][cg] = __builtin_amdgcn_mfma_f32_16x16x32_bf16(av, bwl[t], acc[rr][cg], 0, 0, 0);
                }
            }
        }
    }

    // ---- epilogue: bias, L1-normalize across oc (16-lane shfl), mid, scatter ----
    const float myb = (oc < 8) ? bias[oc] : 0.f;
    const int t = (oc < 8) ? ((oc < 4) ? oc : oc + 1) : 4;
    const bool dow = (oc <= 8);
    const int ii = t / 3, jj = t % 3;
    float* pl = out + ((size_t)(b * 9 + t) * OHH + ii) * OWW + jj;

#pragma unroll
    for (int rr = 0; rr < 4; ++rr) {
        const int h = h0 + wave * 4 + rr;
#pragma unroll
        for (int cg = 0; cg < 2; ++cg) {
#pragma unroll
            for (int reg = 0; reg < 4; ++reg) {
                float vv = acc[rr][cg][reg] + myb;   // lanes oc>=8: 0
                float av = fabsf(vv);
                float sv = vv;
                av += __shfl_xor(av, 1);  sv += __shfl_xor(sv, 1);
                av += __shfl_xor(av, 2);  sv += __shfl_xor(sv, 2);
                av += __shfl_xor(av, 4);  sv += __shfl_xor(sv, 4);
                av += __shfl_xor(av, 8);  sv += __shfl_xor(sv, 8);
                float inv = 1.0f / av;
                float val = (oc == 8) ? (1.0f - sv * inv) : (vv * inv);
                if (dow) {
                    int w = w0 + cg * 16 + hi * 4 + reg;
                    pl[(size_t)h * OWW + w] = val;
                }
            }
        }
    }
}

extern "C" void kernel_launch(void* const* d_in, const int* in_sizes, int n_in,
                              void* d_out, int out_size, void* d_ws, size_t ws_size,
                              hipStream_t stream) {
    const float* feature = (const float*)d_in[0];
    const float* conv_w  = (const float*)d_in[1];
    const float* gamma   = (const float*)d_in[2];
    const float* beta    = (const float*)d_in[3];
    const float* mean    = (const float*)d_in[4];
    const float* var     = (const float*)d_in[5];
    float* out = (float*)d_out;

    unsigned short* wB = (unsigned short*)d_ws;    // 18432 B
    float* bias = (float*)((char*)d_ws + 18432);   // 32 B

    border_kernel<<<BATCH * 9, 256, 0, stream>>>(out);
    repack_kernel<<<5, 256, 0, stream>>>(conv_w, gamma, beta, mean, var, wB, bias);
    conv_mfma<<<NWG, NTHR, 0, stream>>>(feature, wB, bias, out);
}

// Round 18
// 210.375 us; speedup vs baseline: 2.2312x; 1.0114x over previous
//
#include <hip/hip_runtime.h>
#include <hip/hip_bf16.h>

#define BATCH 4
#define CIN 64
#define HH 352
#define WW 1216
#define OCH 8
#define OHH 354
#define OWW 1218
#define HW (HH * WW)

#define BH 16       // output rows per block
#define BW 32       // output cols per block
#define FR 18       // staged rows (halo)
#define FC 34       // staged cols (halo)
#define NPOS (FR * FC)   // 612
#define NTHR 256
#define NHALF 5          // staging tasks per half-pass (2 halves = 10)
#define GX 38            // WW/BW
#define GY 22            // HH/BH
#define NWG (GX * GY * BATCH)   // 3344 = 8 * 418
#define CPX (NWG / 8)           // 418 blocks per XCD

typedef short bf16x8 __attribute__((ext_vector_type(8)));
typedef float f32x4  __attribute__((ext_vector_type(4)));

// fp32 -> bf16 round-to-nearest-even (branchless, finite inputs)
static __device__ __forceinline__ unsigned f2bf(float x) {
    unsigned u = __float_as_uint(x);
    return (u + 0x7FFFu + ((u >> 16) & 1u)) >> 16;
}

// Bake weights into exact MFMA B-fragment layout (bf16, BN-folded, oc>=8 zero):
// wB[(tap*2+cc)*64 + lane] = 8 bf16: B[k = hi*8+j][col = oc], k-channel = cc*32+hi*8+j
__global__ void repack_kernel(const float* __restrict__ conv_w,
                              const float* __restrict__ gamma,
                              const float* __restrict__ beta,
                              const float* __restrict__ mean,
                              const float* __restrict__ var,
                              unsigned short* __restrict__ wB,
                              float* __restrict__ bias)
{
    int tid = blockIdx.x * 256 + threadIdx.x;
    if (tid < 18 * 64) {
        int tc = tid >> 6;          // tap*2 + cc
        int lane = tid & 63;
        int tap = tc >> 1, cc = tc & 1;
        int oc = lane & 15, hi = lane >> 4;
        unsigned v[8];
#pragma unroll
        for (int j = 0; j < 8; ++j) {
            float w = 0.f;
            if (oc < 8) {
                int c = cc * 32 + hi * 8 + j;
                float scl = gamma[oc] * rsqrtf(var[oc] + 1e-5f);
                w = conv_w[((size_t)oc * CIN + c) * 9 + tap] * scl;
            }
            v[j] = f2bf(w);
        }
        uint4 pk;
        pk.x = v[0] | (v[1] << 16);
        pk.y = v[2] | (v[3] << 16);
        pk.z = v[4] | (v[5] << 16);
        pk.w = v[6] | (v[7] << 16);
        ((uint4*)wB)[tid] = pk;
    }
    if (tid < OCH) {
        float scl = gamma[tid] * rsqrtf(var[tid] + 1e-5f);
        bias[tid] = beta[tid] - mean[tid] * scl;
    }
}

// Zero only the uncovered border ring of each (b,t) OUTPUT plane.
__global__ void border_kernel(float* __restrict__ out)
{
    const int bt = blockIdx.x;          // 0..35
    const int t = bt % 9;
    const int i = t / 3, j = t % 3;
    float* pl = out + (size_t)bt * OHH * OWW;
    const int r0 = (i == 0) ? HH : 0;
    const int r1 = (i == 2) ? 1 : (OHH - 1);
    const int c0 = (j == 0) ? WW : 0;
    const int c1 = (j == 2) ? 1 : (OWW - 1);
    const int nrow = 2 * OWW;
    for (int idx = threadIdx.x; idx < 2 * OWW + 2 * OHH; idx += blockDim.x) {
        if (idx < nrow) {
            int r = (idx < OWW) ? r0 : r1;
            int c = (idx < OWW) ? idx : idx - OWW;
            pl[(size_t)r * OWW + c] = 0.f;
        } else {
            int k = idx - nrow;
            int c = (k < OHH) ? c0 : c1;
            int r = (k < OHH) ? k : k - OHH;
            pl[(size_t)r * OWW + c] = 0.f;
        }
    }
}

__global__ __launch_bounds__(NTHR, 2)   // no tighter cap: forced caps spill (r3/r14/r15)
void conv_mfma(const float* __restrict__ feature,
               const unsigned short* __restrict__ wB,
               const float* __restrict__ bias,
               float* __restrict__ out)
{
    __shared__ uint4 sF[NPOS * 4];   // 39424 B, single-buffered

    // Bijective XCD swizzle (nwg = 3344 = 8*418): FETCH 707 -> 320 MB (r14/r16).
    const int lin = blockIdx.x;
    const int wg  = (lin & 7) * CPX + (lin >> 3);
    const int bx  = wg % GX;
    const int byz = wg / GX;
    const int by  = byz % GY;
    const int b   = byz / GY;

    const int tid  = threadIdx.x;
    const int wave = tid >> 6;
    const int lane = tid & 63;
    const int oc   = lane & 15;
    const int hi   = lane >> 4;
    const int h0 = by * BH;
    const int w0 = bx * BW;

    const float* fb = feature + (size_t)b * CIN * HW;
    const int soct = tid & 3;
    const int p0   = tid >> 2;

    f32x4 acc[4][2];
#pragma unroll
    for (int rr = 0; rr < 4; ++rr)
#pragma unroll
        for (int cg = 0; cg < 2; ++cg) acc[rr][cg] = (f32x4)0.f;

#pragma unroll 1
    for (int cc = 0; cc < 2; ++cc) {
        if (cc) __syncthreads();
        const float* chbase = fb + (size_t)(cc * 32 + soct * 8) * HW;

        // Two serialized half-passes of 5 tasks: staging buffer 40 regs not 80.
#pragma unroll 1
        for (int hf = 0; hf < 2; ++hf) {
            float v[NHALF][8];
            float mk5[NHALF];
            int   sl5[NHALF];
#pragma unroll
            for (int it = 0; it < NHALF; ++it) {
                int pos = p0 + (hf * NHALF + it) * 64;
                int cp = (pos < NPOS) ? pos : (NPOS - 1);   // tail: benign duplicate
                int fr = cp / FC;
                int fc = cp - fr * FC;
                int gh = h0 - 1 + fr, gw = w0 - 1 + fc;
                bool ok = ((unsigned)gh < (unsigned)HH) && ((unsigned)gw < (unsigned)WW);
                int sgh = min(max(gh, 0), HH - 1);
                int sgw = min(max(gw, 0), WW - 1);
                const float* sp = chbase + sgh * WW + sgw;
#pragma unroll
                for (int j = 0; j < 8; ++j) v[it][j] = sp[(size_t)j * HW];
                mk5[it] = ok ? 1.f : 0.f;
                sl5[it] = cp * 4 + (soct ^ ((cp >> 1) & 3));
            }
#pragma unroll
            for (int it = 0; it < NHALF; ++it) {
                float mk = mk5[it];
                uint4 pk;
                pk.x = f2bf(v[it][0] * mk) | (f2bf(v[it][1] * mk) << 16);
                pk.y = f2bf(v[it][2] * mk) | (f2bf(v[it][3] * mk) << 16);
                pk.z = f2bf(v[it][4] * mk) | (f2bf(v[it][5] * mk) << 16);
                pk.w = f2bf(v[it][6] * mk) | (f2bf(v[it][7] * mk) << 16);
                sF[sl5[it]] = pk;
            }
        }
        __syncthreads();

        // B-fragments loaded AFTER staging (L2-resident 18KB): bwl's 36 regs no
        // longer live across the 160-load staging phase -> peak pressure drops
        // (116 arch + 32 agpr = 148 total was capping residency at ~2-3 blocks/CU).
        bf16x8 bwl[9];
#pragma unroll
        for (int t = 0; t < 9; ++t)
            bwl[t] = ((const bf16x8*)wB)[(t * 2 + cc) * 64 + lane];

#pragma unroll
        for (int t = 0; t < 9; ++t) {
            const int dh = t / 3, dw = t % 3;
#pragma unroll
            for (int rr = 0; rr < 4; ++rr) {
                const int fr = wave * 4 + rr + dh;
#pragma unroll
                for (int cg = 0; cg < 2; ++cg) {
                    const int fc = cg * 16 + oc + dw;
                    const int pp = fr * FC + fc;
                    bf16x8 av = *reinterpret_cast<const bf16x8*>(&sF[pp * 4 + (hi ^ ((pp >> 1) & 3))]);
                    acc[rr][cg] = __builtin_amdgcn_mfma_f32_16x16x32_bf16(av, bwl[t], acc[rr][cg], 0, 0, 0);
                }
            }
        }
    }

    // ---- epilogue: bias, L1-normalize across oc (16-lane shfl), mid, scatter ----
    const float myb = (oc < 8) ? bias[oc] : 0.f;
    const int t = (oc < 8) ? ((oc < 4) ? oc : oc + 1) : 4;
    const bool dow = (oc <= 8);
    const int ii = t / 3, jj = t % 3;
    float* pl = out + ((size_t)(b * 9 + t) * OHH + ii) * OWW + jj;

#pragma unroll
    for (int rr = 0; rr < 4; ++rr) {
        const int h = h0 + wave * 4 + rr;
#pragma unroll
        for (int cg = 0; cg < 2; ++cg) {
#pragma unroll
            for (int reg = 0; reg < 4; ++reg) {
                float vv = acc[rr][cg][reg] + myb;   // lanes oc>=8: 0
                float av = fabsf(vv);
                float sv = vv;
                av += __shfl_xor(av, 1);  sv += __shfl_xor(sv, 1);
                av += __shfl_xor(av, 2);  sv += __shfl_xor(sv, 2);
                av += __shfl_xor(av, 4);  sv += __shfl_xor(sv, 4);
                av += __shfl_xor(av, 8);  sv += __shfl_xor(sv, 8);
                float inv = 1.0f / av;
                float val = (oc == 8) ? (1.0f - sv * inv) : (vv * inv);
                if (dow) {
                    int w = w0 + cg * 16 + hi * 4 + reg;
                    pl[(size_t)h * OWW + w] = val;
                }
            }
        }
    }
}

extern "C" void kernel_launch(void* const* d_in, const int* in_sizes, int n_in,
                              void* d_out, int out_size, void* d_ws, size_t ws_size,
                              hipStream_t stream) {
    const float* feature = (const float*)d_in[0];
    const float* conv_w  = (const float*)d_in[1];
    const float* gamma   = (const float*)d_in[2];
    const float* beta    = (const float*)d_in[3];
    const float* mean    = (const float*)d_in[4];
    const float* var     = (const float*)d_in[5];
    float* out = (float*)d_out;

    unsigned short* wB = (unsigned short*)d_ws;    // 18432 B
    float* bias = (float*)((char*)d_ws + 18432);   // 32 B

    border_kernel<<<BATCH * 9, 256, 0, stream>>>(out);
    repack_kernel<<<5, 256, 0, stream>>>(conv_w, gamma, beta, mean, var, wB, bias);
    conv_mfma<<<NWG, NTHR, 0, stream>>>(feature, wB, bias, out);
}